// Round 3
// baseline (66.468 us; speedup 1.0000x reference)
//
#include <hip/hip_runtime.h>

// RBF: out[n,m] = exp(-0.5 * max(||A_n||^2 + ||B_m||^2 - 2 A_n.B_m, 0))
// N=M=8192, D=64, fp32 in/out.
// fp16 MFMA cross-term with SWAPPED operands (mfma(bf,af)) so each lane owns
// one output row and 4 consecutive output cols per acc reg -> dwordx4 stores.
// 128x128 tile / 256 threads (4 waves, 2x2 of 64x64), XOR-swizzled LDS.

constexpr int Mdim = 8192;
constexpr int D    = 64;
constexpr int BM   = 128;
constexpr int BN   = 128;
constexpr float NEG_HALF_L2E = -0.72134752044448170f; // -0.5*log2(e)
constexpr float L2E          =  1.44269504088896340f; //  log2(e)

typedef __attribute__((ext_vector_type(8))) _Float16 f16x8;
typedef __attribute__((ext_vector_type(4))) float    f32x4;

__global__ __launch_bounds__(256, 3) void rbf_mfma_58720792871618(
    const float* __restrict__ A, const float* __restrict__ B, float* __restrict__ C)
{
    __shared__ _Float16 Ash[BM * D];   // row-major, 128 B/row, XOR-swizzled slots
    __shared__ _Float16 Bsh[BN * D];
    __shared__ float pA[BM];           // -0.5*log2e * ||row||^2
    __shared__ float pB[BN];

    const int tid  = threadIdx.x;
    const int lane = tid & 63;
    const int wid  = tid >> 6;
    const int row0 = blockIdx.y * BM;
    const int col0 = blockIdx.x * BN;

    // ---------------- stage: fp32 -> fp16 into swizzled LDS + fp32 norms ----------------
    {
        const int r  = tid >> 1;           // tile row 0..127 (A and B)
        const int c0 = (tid & 1) * 32;     // column half
        const float4* ga = reinterpret_cast<const float4*>(A + (size_t)(row0 + r) * D + c0);
        const float4* gb = reinterpret_cast<const float4*>(B + (size_t)(col0 + r) * D + c0);

        float sa = 0.f, sb = 0.f;
        f16x8 ha[4], hb[4];
        #pragma unroll
        for (int k = 0; k < 8; ++k) {
            const float4 v = ga[k];
            sa = fmaf(v.x, v.x, fmaf(v.y, v.y, fmaf(v.z, v.z, fmaf(v.w, v.w, sa))));
            const int t = k >> 1, o = (k & 1) * 4;
            ha[t][o + 0] = (_Float16)v.x; ha[t][o + 1] = (_Float16)v.y;
            ha[t][o + 2] = (_Float16)v.z; ha[t][o + 3] = (_Float16)v.w;
        }
        #pragma unroll
        for (int k = 0; k < 8; ++k) {
            const float4 v = gb[k];
            sb = fmaf(v.x, v.x, fmaf(v.y, v.y, fmaf(v.z, v.z, fmaf(v.w, v.w, sb))));
            const int t = k >> 1, o = (k & 1) * 4;
            hb[t][o + 0] = (_Float16)v.x; hb[t][o + 1] = (_Float16)v.y;
            hb[t][o + 2] = (_Float16)v.z; hb[t][o + 3] = (_Float16)v.w;
        }

        char* abase = reinterpret_cast<char*>(Ash) + r * 128;
        char* bbase = reinterpret_cast<char*>(Bsh) + r * 128;
        #pragma unroll
        for (int t = 0; t < 4; ++t) {
            const int sw = (c0 * 2 + t * 16) ^ ((r & 7) << 4);
            *reinterpret_cast<f16x8*>(abase + sw) = ha[t];
        }
        #pragma unroll
        for (int t = 0; t < 4; ++t) {
            const int sw = (c0 * 2 + t * 16) ^ ((r & 7) << 4);
            *reinterpret_cast<f16x8*>(bbase + sw) = hb[t];
        }

        sa += __shfl_xor(sa, 1);
        sb += __shfl_xor(sb, 1);
        if ((tid & 1) == 0) { pA[r] = NEG_HALF_L2E * sa; pB[r] = NEG_HALF_L2E * sb; }
    }
    __syncthreads();

    // ---------------- MFMA: 64x64 per wave, 4x4 fragments of 16x16, K=64 ----------------
    // Operands SWAPPED: acc[mi][ni] = mfma(bf[ni], af[mi], acc).
    // Output mapping: O[i][j], i=(lane>>4)*4+reg -> B row (output COLUMN),
    //                           j=lane&15        -> A row (output ROW).
    const int wr = (wid >> 1) * 64;    // wave row base in tile
    const int wc = (wid & 1) * 64;     // wave col base in tile
    const int lr = lane & 15;          // A-row within fragment (output row)
    const int kg = lane >> 4;          // k-group; also output col quad base /4

    f32x4 acc[4][4] = {};

    #pragma unroll
    for (int ks = 0; ks < 2; ++ks) {
        f16x8 af[4], bf[4];
        #pragma unroll
        for (int mi = 0; mi < 4; ++mi) {
            const int row = wr + mi * 16 + lr;
            af[mi] = *reinterpret_cast<const f16x8*>(
                reinterpret_cast<const char*>(Ash) + row * 128 +
                ((ks * 64 + kg * 16) ^ ((row & 7) << 4)));
        }
        #pragma unroll
        for (int ni = 0; ni < 4; ++ni) {
            const int col = wc + ni * 16 + lr;
            bf[ni] = *reinterpret_cast<const f16x8*>(
                reinterpret_cast<const char*>(Bsh) + col * 128 +
                ((ks * 64 + kg * 16) ^ ((col & 7) << 4)));
        }
        #pragma unroll
        for (int mi = 0; mi < 4; ++mi)
            #pragma unroll
            for (int ni = 0; ni < 4; ++ni)
                acc[mi][ni] = __builtin_amdgcn_mfma_f32_16x16x32_f16(
                    bf[ni], af[mi], acc[mi][ni], 0, 0, 0);
    }

    // ---------------- epilogue: t = log2e*acc + pa + pb; out = exp2(min(t,0)) ----------------
    // Lane owns row n = row0+wr+mi*16+lr; regs r=0..3 are cols m = col0+wc+ni*16+kg*4+r.
    float4 pb4[4];
    #pragma unroll
    for (int ni = 0; ni < 4; ++ni)
        pb4[ni] = *reinterpret_cast<const float4*>(&pB[wc + ni * 16 + kg * 4]);

    #pragma unroll
    for (int mi = 0; mi < 4; ++mi) {
        const float pa = pA[wr + mi * 16 + lr];
        float* crow = C + (size_t)(row0 + wr + mi * 16 + lr) * Mdim + (col0 + wc + kg * 4);
        #pragma unroll
        for (int ni = 0; ni < 4; ++ni) {
            float4 o;
            o.x = __builtin_amdgcn_exp2f(fminf(fmaf(L2E, acc[mi][ni][0], pa + pb4[ni].x), 0.0f));
            o.y = __builtin_amdgcn_exp2f(fminf(fmaf(L2E, acc[mi][ni][1], pa + pb4[ni].y), 0.0f));
            o.z = __builtin_amdgcn_exp2f(fminf(fmaf(L2E, acc[mi][ni][2], pa + pb4[ni].z), 0.0f));
            o.w = __builtin_amdgcn_exp2f(fminf(fmaf(L2E, acc[mi][ni][3], pa + pb4[ni].w), 0.0f));
            *reinterpret_cast<float4*>(crow + ni * 16) = o;
        }
    }
}

extern "C" void kernel_launch(void* const* d_in, const int* /*in_sizes*/, int /*n_in*/,
                              void* d_out, int /*out_size*/, void* /*d_ws*/, size_t /*ws_size*/,
                              hipStream_t stream)
{
    const float* A = (const float*)d_in[0];   // input_1 [8192, 64]
    const float* B = (const float*)d_in[1];   // input_2 [8192, 64]
    float* C = (float*)d_out;                 // [8192, 8192]
    dim3 grid(Mdim / BN, 8192 / BM);
    rbf_mfma_58720792871618<<<grid, 256, 0, stream>>>(A, B, C);
}

// Round 4
// 55.837 us; speedup vs baseline: 1.1904x; 1.1904x over previous
//
#include <hip/hip_runtime.h>

// RBF: out[n,m] = exp(-0.5 * max(||A_n||^2 + ||B_m||^2 - 2 A_n.B_m, 0))
// N=M=8192, D=64, fp32 in/out.
// fp16 32x32x16 MFMA cross-term (non-swapped), exact fp32 norms, exp2 epilogue.
// Store instr = 2 rows x 128 B contiguous (lower row-concentration than 16x16 path).
// 128x128 tile / 256 threads (4 waves, 2x2 of 64x64), XOR-swizzled LDS.

constexpr int Mdim = 8192;
constexpr int D    = 64;
constexpr int BM   = 128;
constexpr int BN   = 128;
constexpr float NEG_HALF_L2E = -0.72134752044448170f; // -0.5*log2(e)
constexpr float L2E          =  1.44269504088896340f; //  log2(e)

typedef __attribute__((ext_vector_type(8)))  _Float16 f16x8;
typedef __attribute__((ext_vector_type(16))) float    f32x16;

__global__ __launch_bounds__(256, 3) void rbf_mfma_58720792871618(
    const float* __restrict__ A, const float* __restrict__ B, float* __restrict__ C)
{
    __shared__ _Float16 Ash[BM * D];   // row-major, 128 B/row, XOR-swizzled 16B slots
    __shared__ _Float16 Bsh[BN * D];
    __shared__ float pA[BM];           // -0.5*log2e * ||row||^2
    __shared__ float pB[BN];

    const int tid  = threadIdx.x;
    const int lane = tid & 63;
    const int wid  = tid >> 6;
    const int row0 = blockIdx.y * BM;
    const int col0 = blockIdx.x * BN;

    // ---------------- stage: fp32 -> fp16 into swizzled LDS + fp32 norms ----------------
    {
        const int r  = tid >> 1;           // tile row 0..127 (A and B)
        const int c0 = (tid & 1) * 32;     // column half
        const float4* ga = reinterpret_cast<const float4*>(A + (size_t)(row0 + r) * D + c0);
        const float4* gb = reinterpret_cast<const float4*>(B + (size_t)(col0 + r) * D + c0);

        float sa = 0.f, sb = 0.f;
        f16x8 ha[4], hb[4];
        #pragma unroll
        for (int k = 0; k < 8; ++k) {
            const float4 v = ga[k];
            sa = fmaf(v.x, v.x, fmaf(v.y, v.y, fmaf(v.z, v.z, fmaf(v.w, v.w, sa))));
            const int t = k >> 1, o = (k & 1) * 4;
            ha[t][o + 0] = (_Float16)v.x; ha[t][o + 1] = (_Float16)v.y;
            ha[t][o + 2] = (_Float16)v.z; ha[t][o + 3] = (_Float16)v.w;
        }
        #pragma unroll
        for (int k = 0; k < 8; ++k) {
            const float4 v = gb[k];
            sb = fmaf(v.x, v.x, fmaf(v.y, v.y, fmaf(v.z, v.z, fmaf(v.w, v.w, sb))));
            const int t = k >> 1, o = (k & 1) * 4;
            hb[t][o + 0] = (_Float16)v.x; hb[t][o + 1] = (_Float16)v.y;
            hb[t][o + 2] = (_Float16)v.z; hb[t][o + 3] = (_Float16)v.w;
        }

        char* abase = reinterpret_cast<char*>(Ash) + r * 128;
        char* bbase = reinterpret_cast<char*>(Bsh) + r * 128;
        #pragma unroll
        for (int t = 0; t < 4; ++t) {
            const int sw = (c0 * 2 + t * 16) ^ ((r & 7) << 4);
            *reinterpret_cast<f16x8*>(abase + sw) = ha[t];
        }
        #pragma unroll
        for (int t = 0; t < 4; ++t) {
            const int sw = (c0 * 2 + t * 16) ^ ((r & 7) << 4);
            *reinterpret_cast<f16x8*>(bbase + sw) = hb[t];
        }

        sa += __shfl_xor(sa, 1);
        sb += __shfl_xor(sb, 1);
        if ((tid & 1) == 0) { pA[r] = NEG_HALF_L2E * sa; pB[r] = NEG_HALF_L2E * sb; }
    }
    __syncthreads();

    // ---------------- MFMA: 64x64 per wave, 2x2 fragments of 32x32, K=64 ----------------
    // A-frag: row = lane&31, k = (lane>>5)*8 + e  (per 16-wide K step)
    // C/D:    col = lane&31, row = (reg&3) + 8*(reg>>2) + 4*(lane>>5)
    const int wr  = (wid >> 1) * 64;   // wave row base in tile
    const int wc  = (wid & 1) * 64;    // wave col base in tile
    const int l31 = lane & 31;
    const int hi  = lane >> 5;

    const int arow0 = wr + l31,  arow1 = wr + 32 + l31;
    const int brow0 = wc + l31,  brow1 = wc + 32 + l31;
    const char* ab = reinterpret_cast<const char*>(Ash);
    const char* bb = reinterpret_cast<const char*>(Bsh);

    f32x16 acc[2][2] = {};

    #pragma unroll
    for (int ks = 0; ks < 4; ++ks) {
        const int kb = ks * 32 + hi * 16;   // byte offset of this lane's k-slice
        f16x8 af[2], bf[2];
        af[0] = *reinterpret_cast<const f16x8*>(ab + arow0 * 128 + (kb ^ ((arow0 & 7) << 4)));
        af[1] = *reinterpret_cast<const f16x8*>(ab + arow1 * 128 + (kb ^ ((arow1 & 7) << 4)));
        bf[0] = *reinterpret_cast<const f16x8*>(bb + brow0 * 128 + (kb ^ ((brow0 & 7) << 4)));
        bf[1] = *reinterpret_cast<const f16x8*>(bb + brow1 * 128 + (kb ^ ((brow1 & 7) << 4)));
        #pragma unroll
        for (int mf = 0; mf < 2; ++mf)
            #pragma unroll
            for (int nf = 0; nf < 2; ++nf)
                acc[mf][nf] = __builtin_amdgcn_mfma_f32_32x32x16_f16(
                    af[mf], bf[nf], acc[mf][nf], 0, 0, 0);
    }

    // ---------------- epilogue: t = log2e*acc + pa + pb; out = exp2(min(t,0)) ----------------
    // Store: scalar dword; per instr lanes 0-31 = one row (128 B contiguous),
    // lanes 32-63 = row+4 -> 2 rows x 128 B per instruction.
    const float pb0 = pB[wc + l31];
    const float pb1 = pB[wc + 32 + l31];

    #pragma unroll
    for (int mf = 0; mf < 2; ++mf) {
        #pragma unroll
        for (int g = 0; g < 4; ++g) {
            #pragma unroll
            for (int q = 0; q < 4; ++q) {
                const int rt = wr + mf * 32 + 4 * hi + 8 * g + q;   // row in tile
                const float pav = pA[rt];
                float* crow = C + (size_t)(row0 + rt) * Mdim + (col0 + wc + l31);
                const int e = g * 4 + q;
                float t0 = fmaf(L2E, acc[mf][0][e], pav + pb0);
                float t1 = fmaf(L2E, acc[mf][1][e], pav + pb1);
                crow[0]  = __builtin_amdgcn_exp2f(fminf(t0, 0.0f));
                crow[32] = __builtin_amdgcn_exp2f(fminf(t1, 0.0f));
            }
        }
    }
}

extern "C" void kernel_launch(void* const* d_in, const int* /*in_sizes*/, int /*n_in*/,
                              void* d_out, int /*out_size*/, void* /*d_ws*/, size_t /*ws_size*/,
                              hipStream_t stream)
{
    const float* A = (const float*)d_in[0];   // input_1 [8192, 64]
    const float* B = (const float*)d_in[1];   // input_2 [8192, 64]
    float* C = (float*)d_out;                 // [8192, 8192]
    dim3 grid(Mdim / BN, 8192 / BM);
    rbf_mfma_58720792871618<<<grid, 256, 0, stream>>>(A, B, C);
}

// Round 5
// 53.568 us; speedup vs baseline: 1.2408x; 1.0423x over previous
//
#include <hip/hip_runtime.h>

// RBF: out[n,m] = exp(-0.5 * max(||A_n||^2 + ||B_m||^2 - 2 A_n.B_m, 0))
// N=M=8192, D=64, fp32 in/out.
// fp16 32x32x16 MFMA cross-term, exact fp32 norms, exp2 epilogue.
// Round 5 change: NONTEMPORAL C-stores so the 268 MB write stream doesn't
// evict the L2-resident A/B panels (read 64x each).
// 128x128 tile / 256 threads (4 waves, 2x2 of 64x64), XOR-swizzled LDS.

constexpr int Mdim = 8192;
constexpr int D    = 64;
constexpr int BM   = 128;
constexpr int BN   = 128;
constexpr float NEG_HALF_L2E = -0.72134752044448170f; // -0.5*log2(e)
constexpr float L2E          =  1.44269504088896340f; //  log2(e)

typedef __attribute__((ext_vector_type(8)))  _Float16 f16x8;
typedef __attribute__((ext_vector_type(16))) float    f32x16;

__global__ __launch_bounds__(256, 3) void rbf_mfma_58720792871618(
    const float* __restrict__ A, const float* __restrict__ B, float* __restrict__ C)
{
    __shared__ _Float16 Ash[BM * D];   // row-major, 128 B/row, XOR-swizzled 16B slots
    __shared__ _Float16 Bsh[BN * D];
    __shared__ float pA[BM];           // -0.5*log2e * ||row||^2
    __shared__ float pB[BN];

    const int tid  = threadIdx.x;
    const int lane = tid & 63;
    const int wid  = tid >> 6;
    const int row0 = blockIdx.y * BM;
    const int col0 = blockIdx.x * BN;

    // ---------------- stage: fp32 -> fp16 into swizzled LDS + fp32 norms ----------------
    {
        const int r  = tid >> 1;           // tile row 0..127 (A and B)
        const int c0 = (tid & 1) * 32;     // column half
        const float4* ga = reinterpret_cast<const float4*>(A + (size_t)(row0 + r) * D + c0);
        const float4* gb = reinterpret_cast<const float4*>(B + (size_t)(col0 + r) * D + c0);

        float sa = 0.f, sb = 0.f;
        f16x8 ha[4], hb[4];
        #pragma unroll
        for (int k = 0; k < 8; ++k) {
            const float4 v = ga[k];
            sa = fmaf(v.x, v.x, fmaf(v.y, v.y, fmaf(v.z, v.z, fmaf(v.w, v.w, sa))));
            const int t = k >> 1, o = (k & 1) * 4;
            ha[t][o + 0] = (_Float16)v.x; ha[t][o + 1] = (_Float16)v.y;
            ha[t][o + 2] = (_Float16)v.z; ha[t][o + 3] = (_Float16)v.w;
        }
        #pragma unroll
        for (int k = 0; k < 8; ++k) {
            const float4 v = gb[k];
            sb = fmaf(v.x, v.x, fmaf(v.y, v.y, fmaf(v.z, v.z, fmaf(v.w, v.w, sb))));
            const int t = k >> 1, o = (k & 1) * 4;
            hb[t][o + 0] = (_Float16)v.x; hb[t][o + 1] = (_Float16)v.y;
            hb[t][o + 2] = (_Float16)v.z; hb[t][o + 3] = (_Float16)v.w;
        }

        char* abase = reinterpret_cast<char*>(Ash) + r * 128;
        char* bbase = reinterpret_cast<char*>(Bsh) + r * 128;
        #pragma unroll
        for (int t = 0; t < 4; ++t) {
            const int sw = (c0 * 2 + t * 16) ^ ((r & 7) << 4);
            *reinterpret_cast<f16x8*>(abase + sw) = ha[t];
        }
        #pragma unroll
        for (int t = 0; t < 4; ++t) {
            const int sw = (c0 * 2 + t * 16) ^ ((r & 7) << 4);
            *reinterpret_cast<f16x8*>(bbase + sw) = hb[t];
        }

        sa += __shfl_xor(sa, 1);
        sb += __shfl_xor(sb, 1);
        if ((tid & 1) == 0) { pA[r] = NEG_HALF_L2E * sa; pB[r] = NEG_HALF_L2E * sb; }
    }
    __syncthreads();

    // ---------------- MFMA: 64x64 per wave, 2x2 fragments of 32x32, K=64 ----------------
    // A-frag: row = lane&31, k = (lane>>5)*8 + e  (per 16-wide K step)
    // C/D:    col = lane&31, row = (reg&3) + 8*(reg>>2) + 4*(lane>>5)
    const int wr  = (wid >> 1) * 64;   // wave row base in tile
    const int wc  = (wid & 1) * 64;    // wave col base in tile
    const int l31 = lane & 31;
    const int hi  = lane >> 5;

    const int arow0 = wr + l31,  arow1 = wr + 32 + l31;
    const int brow0 = wc + l31,  brow1 = wc + 32 + l31;
    const char* ab = reinterpret_cast<const char*>(Ash);
    const char* bb = reinterpret_cast<const char*>(Bsh);

    f32x16 acc[2][2] = {};

    #pragma unroll
    for (int ks = 0; ks < 4; ++ks) {
        const int kb = ks * 32 + hi * 16;   // byte offset of this lane's k-slice
        f16x8 af[2], bf[2];
        af[0] = *reinterpret_cast<const f16x8*>(ab + arow0 * 128 + (kb ^ ((arow0 & 7) << 4)));
        af[1] = *reinterpret_cast<const f16x8*>(ab + arow1 * 128 + (kb ^ ((arow1 & 7) << 4)));
        bf[0] = *reinterpret_cast<const f16x8*>(bb + brow0 * 128 + (kb ^ ((brow0 & 7) << 4)));
        bf[1] = *reinterpret_cast<const f16x8*>(bb + brow1 * 128 + (kb ^ ((brow1 & 7) << 4)));
        #pragma unroll
        for (int mf = 0; mf < 2; ++mf)
            #pragma unroll
            for (int nf = 0; nf < 2; ++nf)
                acc[mf][nf] = __builtin_amdgcn_mfma_f32_32x32x16_f16(
                    af[mf], bf[nf], acc[mf][nf], 0, 0, 0);
    }

    // ---------------- epilogue: t = log2e*acc + pa + pb; out = exp2(min(t,0)) ----------------
    // Nontemporal scalar-dword stores: 2 rows x 128 B contiguous per instruction,
    // nt bit keeps the write stream from evicting A/B panels out of L2.
    const float pb0 = pB[wc + l31];
    const float pb1 = pB[wc + 32 + l31];

    #pragma unroll
    for (int mf = 0; mf < 2; ++mf) {
        #pragma unroll
        for (int g = 0; g < 4; ++g) {
            #pragma unroll
            for (int q = 0; q < 4; ++q) {
                const int rt = wr + mf * 32 + 4 * hi + 8 * g + q;   // row in tile
                const float pav = pA[rt];
                float* crow = C + (size_t)(row0 + rt) * Mdim + (col0 + wc + l31);
                const int e = g * 4 + q;
                float t0 = fmaf(L2E, acc[mf][0][e], pav + pb0);
                float t1 = fmaf(L2E, acc[mf][1][e], pav + pb1);
                __builtin_nontemporal_store(
                    __builtin_amdgcn_exp2f(fminf(t0, 0.0f)), crow + 0);
                __builtin_nontemporal_store(
                    __builtin_amdgcn_exp2f(fminf(t1, 0.0f)), crow + 32);
            }
        }
    }
}

extern "C" void kernel_launch(void* const* d_in, const int* /*in_sizes*/, int /*n_in*/,
                              void* d_out, int /*out_size*/, void* /*d_ws*/, size_t /*ws_size*/,
                              hipStream_t stream)
{
    const float* A = (const float*)d_in[0];   // input_1 [8192, 64]
    const float* B = (const float*)d_in[1];   // input_2 [8192, 64]
    float* C = (float*)d_out;                 // [8192, 8192]
    dim3 grid(Mdim / BN, 8192 / BM);
    rbf_mfma_58720792871618<<<grid, 256, 0, stream>>>(A, B, C);
}